// Round 1
// baseline (747.680 us; speedup 1.0000x reference)
//
#include <hip/hip_runtime.h>
#include <utility>

#define DEVI __device__ __forceinline__

namespace {

constexpr int T_ = 128;
constexpr int NCH = 96;
constexpr int CT = NCH * T_;          // 12288
constexpr int NJ = 24;
constexpr int ZDIM = 256;
constexpr int NP = 512;               // Bp
constexpr int PAR[NJ] = {0,0,0,0,1,2,3,4,5,6,7,8,9,9,9,12,13,14,16,17,18,19,20,21};

struct Q  { float w,x,y,z; };
struct V3 { float x,y,z; };

DEVI Q qmul(Q a, Q b){
  return Q{ a.w*b.w - a.x*b.x - a.y*b.y - a.z*b.z,
            a.w*b.x + a.x*b.w + a.y*b.z - a.z*b.y,
            a.w*b.y - a.x*b.z + a.y*b.w + a.z*b.x,
            a.w*b.z + a.x*b.y - a.y*b.x + a.z*b.w };
}
DEVI Q qconj(Q a){ return Q{a.w,-a.x,-a.y,-a.z}; }
DEVI float qn2(Q a){ return a.w*a.w + a.x*a.x + a.y*a.y + a.z*a.z; }
DEVI Q qscale(Q a, float s){ return Q{a.w*s, a.x*s, a.y*s, a.z*s}; }
DEVI Q qadd(Q a, Q b){ return Q{a.w+b.w, a.x+b.x, a.y+b.y, a.z+b.z}; }
DEVI Q qinv(Q a){ return qscale(qconj(a), 1.0f/qn2(a)); }
DEVI V3 qrot(Q g, V3 v){
  Q t = qmul(g, Q{0.f, v.x, v.y, v.z});
  Q y = qmul(t, qconj(g));
  float in = 1.0f/qn2(g);
  return V3{y.x*in, y.y*in, y.z*in};
}
// cot g on y = qinv(q) -> dq
DEVI Q qinv_bwd(Q q, Q g){
  float n  = qn2(q);
  float in = 1.0f/n;
  float d  = g.w*q.w - g.x*q.x - g.y*q.y - g.z*q.z;   // g . conj(q)
  float c  = 2.0f*d*in*in;
  return Q{ g.w*in - q.w*c, -g.x*in - q.x*c, -g.y*in - q.y*c, -g.z*in - q.z*c };
}
// cot w (3-vec) on out = qrot(g, v) -> dg
DEVI Q qrot_bwd_g(Q g, V3 v, V3 w){
  float in = 1.0f/qn2(g);
  Q u{0.f, v.x, v.y, v.z};
  Q t = qmul(g, u);
  Q y = qmul(t, qconj(g));
  Q G4{0.f, w.x*in, w.y*in, w.z*in};
  Q dt  = qmul(G4, g);            // y = t (x) conj(g): dt = G4 (x) conj(conj g) = G4 (x) g
  Q dcg = qmul(qconj(t), G4);     // d conj(g) = conj(t) (x) G4
  Q dg  = qconj(dcg);
  dg = qadd(dg, qmul(dt, qconj(u)));
  float wy = w.x*y.x + w.y*y.y + w.z*y.z;
  dg = qadd(dg, qscale(g, -2.0f*wy*in*in));
  return dg;
}

template<typename F, int... Is>
DEVI void sf_impl(F&& f, std::integer_sequence<int, Is...>){
  (f(std::integral_constant<int, Is>{}), ...);
}
template<int N, typename F>
DEVI void static_for(F&& f){ sf_impl(f, std::make_integer_sequence<int, N>{}); }

template<int Jj>
DEVI Q loadQ(const float (&q)[NJ][4]){ return Q{q[Jj][0], q[Jj][1], q[Jj][2], q[Jj][3]}; }
template<int Jj>
DEVI Q localQ(const float (&q)[NJ][4]){
  if constexpr (Jj < 4) return loadQ<Jj>(q);
  else return qmul(qinv(loadQ<PAR[Jj]>(q)), loadQ<Jj>(q));
}
template<int Jj>
DEVI Q grotRec(const float (&q)[NJ][4]){
  if constexpr (Jj == 0) return Q{1.f,0.f,0.f,0.f};
  else return qmul(grotRec<PAR[Jj]>(q), localQ<Jj>(q));
}

// Forward chain: loads raw channels, scales, root=identity, from_root -> fk.
// pj(jc, gpos_j) called for every joint (incl. j=0 with zero pos).
template<bool TGT, typename PJ>
DEVI void chainFwd(const float* __restrict__ base, int t,
                   const float* s_std, const float* s_mean, const float* s_off,
                   float (&q)[NJ][4], PJ&& pj)
{
  Q grot[NJ]; V3 gpos[NJ];
  static_for<NJ>([&](auto jc){
    constexpr int j = decltype(jc)::value;
    if constexpr (j == 0) {
      q[0][0]=1.f; q[0][1]=0.f; q[0][2]=0.f; q[0][3]=0.f;
      grot[0] = Q{1.f,0.f,0.f,0.f};
      gpos[0] = V3{0.f,0.f,0.f};
    } else {
      constexpr int P = PAR[j];
      #pragma unroll
      for (int i = 0; i < 4; ++i){
        const int c  = 4*j + i;
        const int oc = TGT ? (8*j + i) : c;
        q[j][i] = base[oc*T_ + t] * s_std[c] + s_mean[c];
      }
      Q qj{q[j][0], q[j][1], q[j][2], q[j][3]};
      Q L;
      if constexpr (j < 4) L = qj;
      else L = qmul(qinv(Q{q[P][0], q[P][1], q[P][2], q[P][3]}), qj);
      Q gP = grot[P];
      grot[j] = qmul(gP, L);
      V3 o{s_off[3*j], s_off[3*j+1], s_off[3*j+2]};
      V3 r = qrot(gP, o);
      gpos[j] = V3{gpos[P].x + r.x, gpos[P].y + r.y, gpos[P].z + r.z};
    }
    pj(jc, gpos[j]);
  });
}

// Backward through fk + from_root + scale for the k=0 decoded chain.
DEVI void chainBwd(const float (&q)[NJ][4], const float* s_std, const float* s_off,
                   V3 (&dgp)[NJ], float* __restrict__ Gp, int t)
{
  Q dgr[NJ] = {};
  Q dq [NJ] = {};
  static_for<NJ-1>([&](auto ic){
    constexpr int j = NJ - 1 - decltype(ic)::value;   // 23..1
    constexpr int P = PAR[j];
    V3 w = dgp[j];
    Q gP = grotRec<P>(q);
    if constexpr (P != 0) {
      dgp[P].x += w.x; dgp[P].y += w.y; dgp[P].z += w.z;
      V3 o{s_off[3*j], s_off[3*j+1], s_off[3*j+2]};
      dgr[P] = qadd(dgr[P], qrot_bwd_g(gP, o, w));
    }
    Q Gj = dgr[j];
    Q dL = qmul(qconj(gP), Gj);
    if constexpr (P != 0) {
      dgr[P] = qadd(dgr[P], qmul(Gj, qconj(localQ<j>(q))));
    }
    if constexpr (j < 4) {
      dq[j] = qadd(dq[j], dL);
    } else {
      Q qP  = loadQ<P>(q);
      Q iqP = qinv(qP);
      dq[j] = qadd(dq[j], qmul(qconj(iqP), dL));
      Q dInv = qmul(dL, qconj(loadQ<j>(q)));
      dq[P] = qadd(dq[P], qinv_bwd(qP, dInv));
    }
    Gp[(4*j+0)*T_ + t] = dq[j].w * s_std[4*j+0];
    Gp[(4*j+1)*T_ + t] = dq[j].x * s_std[4*j+1];
    Gp[(4*j+2)*T_ + t] = dq[j].y * s_std[4*j+2];
    Gp[(4*j+3)*T_ + t] = dq[j].z * s_std[4*j+3];
  });
  #pragma unroll
  for (int i = 0; i < 4; ++i) Gp[i*T_ + t] = 0.f;   // root channels: grad 0
}

DEVI float waveSum(float v){
  #pragma unroll
  for (int o = 32; o > 0; o >>= 1) v += __shfl_down(v, o);
  return v;
}

} // namespace

// ---------------- kernels ----------------

__global__ void k_zero(float* accum){
  if (threadIdx.x < 8) accum[threadIdx.x] = 0.f;
}

// qs = base_motion + lat @ W_dec : M=1024, N=12288, K=256
__global__ __launch_bounds__(256) void k_decode(
    const float* __restrict__ base, const float* __restrict__ lat,
    const float* __restrict__ W, float* __restrict__ qs)
{
  __shared__ float As[32][132];   // A^T [k][m]
  __shared__ float Bs[32][128];
  const int tid = threadIdx.x;
  const int bn = blockIdx.x * 128;
  const int bm = blockIdx.y * 128;
  float acc[8][8] = {};
  for (int k0 = 0; k0 < 256; k0 += 32) {
    #pragma unroll
    for (int r = 0; r < 4; ++r) {
      int idx = r*256 + tid;           // 1024 float4
      int row = idx >> 3;              // 0..127
      int kc  = (idx & 7) << 2;
      float4 v = *(const float4*)&lat[(size_t)(bm + row)*256 + k0 + kc];
      As[kc+0][row] = v.x; As[kc+1][row] = v.y;
      As[kc+2][row] = v.z; As[kc+3][row] = v.w;
    }
    #pragma unroll
    for (int r = 0; r < 4; ++r) {
      int idx = r*256 + tid;
      int kr = idx >> 5;               // 0..31
      int nc = (idx & 31) << 2;        // 0..124
      *(float4*)&Bs[kr][nc] = *(const float4*)&W[(size_t)(k0 + kr)*CT + bn + nc];
    }
    __syncthreads();
    const int tx = tid & 15, ty = tid >> 4;
    #pragma unroll
    for (int kk = 0; kk < 32; ++kk) {
      float a[8], b[8];
      float4 a0 = *(float4*)&As[kk][ty*8];
      float4 a1 = *(float4*)&As[kk][ty*8+4];
      float4 b0 = *(float4*)&Bs[kk][tx*8];
      float4 b1 = *(float4*)&Bs[kk][tx*8+4];
      a[0]=a0.x;a[1]=a0.y;a[2]=a0.z;a[3]=a0.w;a[4]=a1.x;a[5]=a1.y;a[6]=a1.z;a[7]=a1.w;
      b[0]=b0.x;b[1]=b0.y;b[2]=b0.z;b[3]=b0.w;b[4]=b1.x;b[5]=b1.y;b[6]=b1.z;b[7]=b1.w;
      #pragma unroll
      for (int i = 0; i < 8; ++i)
        #pragma unroll
        for (int j = 0; j < 8; ++j) acc[i][j] += a[i]*b[j];
    }
    __syncthreads();
  }
  const int tx = tid & 15, ty = tid >> 4;
  #pragma unroll
  for (int i = 0; i < 8; ++i) {
    size_t row = bm + ty*8 + i;
    #pragma unroll
    for (int j = 0; j < 8; j += 4) {
      size_t col = bn + tx*8 + j;
      float4 bv = *(const float4*)&base[row*CT + col];
      float4 o;
      o.x = bv.x + acc[i][j+0]; o.y = bv.y + acc[i][j+1];
      o.z = bv.z + acc[i][j+2]; o.w = bv.w + acc[i][j+3];
      *(float4*)&qs[row*CT + col] = o;
    }
  }
}

// Per (p,t): elementwise root/joint losses, 4 FK chains, fk loss, backward -> G
__global__ __launch_bounds__(128, 1) void k_pose(
    const float* __restrict__ qs,   const float* __restrict__ tmot,
    const float* __restrict__ meanq,const float* __restrict__ stdq,
    const float* __restrict__ offs, float* __restrict__ G,
    float* __restrict__ accum)
{
  __shared__ float s_std[96], s_mean[96], s_off[72];
  const int p = blockIdx.x;
  const int t = threadIdx.x;
  if (t < 96) { s_std[t] = stdq[t]; s_mean[t] = meanq[t]; }
  if (t < 72) s_off[t] = offs[p*72 + t];
  __syncthreads();

  const float* qs0 = qs   + (size_t)(2*p) * CT;
  const float* qs1 = qs0  + CT;
  const float* tm0 = tmot + (size_t)(2*p) * (2*CT);
  const float* tm1 = tm0  + 2*CT;

  // elementwise quaternion losses (raw, unscaled)
  float accR = 0.f, accJ = 0.f;
  #pragma unroll 4
  for (int c = 0; c < 4; ++c) {
    int oc = ((c >> 2) << 3) + (c & 3);
    float d0 = qs0[c*T_ + t] - tm0[oc*T_ + t];
    float d1 = qs1[c*T_ + t] - tm1[oc*T_ + t];
    accR += d0*d0 + d1*d1;
  }
  #pragma unroll 4
  for (int c = 4; c < 96; ++c) {
    int oc = ((c >> 2) << 3) + (c & 3);
    float d0 = qs0[c*T_ + t] - tm0[oc*T_ + t];
    float d1 = qs1[c*T_ + t] - tm1[oc*T_ + t];
    accJ += d0*d0 + d1*d1;
  }

  float fkAcc = 0.f;
  V3 posA[NJ], posB[NJ];
  float qtmp[NJ][4], qd0[NJ][4];

  chainFwd<true >(tm0, t, s_std, s_mean, s_off, qtmp,
    [&](auto jc, V3 g){ posA[decltype(jc)::value] = g; });
  chainFwd<false>(qs0, t, s_std, s_mean, s_off, qd0,
    [&](auto jc, V3 g){
      constexpr int j = decltype(jc)::value;
      float dx = g.x - posA[j].x, dy = g.y - posA[j].y, dz = g.z - posA[j].z;
      fkAcc += dx*dx + dy*dy + dz*dz;
      posB[j] = g;
    });
  chainFwd<true >(tm1, t, s_std, s_mean, s_off, qtmp,
    [&](auto jc, V3 g){ posA[decltype(jc)::value] = g; });
  V3 dgp[NJ];
  chainFwd<false>(qs1, t, s_std, s_mean, s_off, qtmp,
    [&](auto jc, V3 g){
      constexpr int j = decltype(jc)::value;
      float dx = g.x - posA[j].x, dy = g.y - posA[j].y, dz = g.z - posA[j].z;
      fkAcc += dx*dx + dy*dy + dz*dz;
      dgp[j] = V3{2.f*(posB[j].x - g.x), 2.f*(posB[j].y - g.y), 2.f*(posB[j].z - g.z)};
    });

  chainBwd(qd0, s_std, s_off, dgp, G + (size_t)p * CT, t);

  float r  = waveSum(accR);
  float jj = waveSum(accJ);
  float fk = waveSum(fkAcc);
  if ((t & 63) == 0) {
    atomicAdd(&accum[0], r);
    atomicAdd(&accum[1], jj);
    atomicAdd(&accum[2], fk);
  }
}

// grad partials: part[s][p][z] = sum over K-chunk of G[p][k]*W[z][k]
// M=512(p), N=256(z), K=12288; BM=64, BN=128, BK=32, SPLITK=16
__global__ __launch_bounds__(256) void k_gradgemm(
    const float* __restrict__ G, const float* __restrict__ W,
    float* __restrict__ part)
{
  __shared__ float As[64][33];
  __shared__ float Bs[128][33];
  const int tid = threadIdx.x;
  const int bn = blockIdx.x * 128;
  const int bm = blockIdx.y * 64;
  const int s  = blockIdx.z;
  const int kb = s * 768;
  float acc[4][8] = {};
  for (int k0 = 0; k0 < 768; k0 += 32) {
    #pragma unroll
    for (int r = 0; r < 2; ++r) {
      int idx = r*256 + tid;          // 512 float4
      int row = idx >> 3;             // 0..63
      int kc  = (idx & 7) << 2;
      float4 v = *(const float4*)&G[(size_t)(bm + row)*CT + kb + k0 + kc];
      As[row][kc+0]=v.x; As[row][kc+1]=v.y; As[row][kc+2]=v.z; As[row][kc+3]=v.w;
    }
    #pragma unroll
    for (int r = 0; r < 4; ++r) {
      int idx = r*256 + tid;          // 1024 float4
      int row = idx >> 3;             // 0..127
      int kc  = (idx & 7) << 2;
      float4 v = *(const float4*)&W[(size_t)(bn + row)*CT + kb + k0 + kc];
      Bs[row][kc+0]=v.x; Bs[row][kc+1]=v.y; Bs[row][kc+2]=v.z; Bs[row][kc+3]=v.w;
    }
    __syncthreads();
    const int tx = tid & 15, ty = tid >> 4;
    #pragma unroll
    for (int kk = 0; kk < 32; ++kk) {
      float a[4], b[8];
      #pragma unroll
      for (int i = 0; i < 4; ++i) a[i] = As[ty*4+i][kk];
      #pragma unroll
      for (int j = 0; j < 8; ++j) b[j] = Bs[tx*8+j][kk];
      #pragma unroll
      for (int i = 0; i < 4; ++i)
        #pragma unroll
        for (int j = 0; j < 8; ++j) acc[i][j] += a[i]*b[j];
    }
    __syncthreads();
  }
  const int tx = tid & 15, ty = tid >> 4;
  #pragma unroll
  for (int i = 0; i < 4; ++i) {
    size_t pr = (size_t)s*131072 + (size_t)(bm + ty*4 + i)*256 + bn + tx*8;
    float4 o0{acc[i][0], acc[i][1], acc[i][2], acc[i][3]};
    float4 o1{acc[i][4], acc[i][5], acc[i][6], acc[i][7]};
    *(float4*)&part[pr]   = o0;
    *(float4*)&part[pr+4] = o1;
  }
}

// disp / kld / cons reductions
__global__ __launch_bounds__(256) void k_rest(
    const float* __restrict__ ind, const float* __restrict__ tgd,
    const float* __restrict__ mu,  const float* __restrict__ lv,
    const float* __restrict__ lat, const float* __restrict__ part,
    float* __restrict__ accum)
{
  const int idx = blockIdx.x * 256 + threadIdx.x;
  float a0 = 0.f, a1 = 0.f, a2 = 0.f;
  if (idx < 393216) { float d = ind[idx] - tgd[idx]; a0 = d*d; }
  if (idx < 262144) { float l = lv[idx], m = mu[idx]; a1 = 1.f + l - m*m - expf(l); }
  if (idx < 131072) {
    float g = 0.f;
    #pragma unroll
    for (int s = 0; s < 16; ++s) g += part[s*131072 + idx];
    int p = idx >> 8, z = idx & 255;
    float v = lat[(size_t)(2*p)*ZDIM + z] - g - lat[(size_t)(2*p+1)*ZDIM + z];
    a2 = v*v;
  }
  a0 = waveSum(a0); a1 = waveSum(a1); a2 = waveSum(a2);
  if ((threadIdx.x & 63) == 0) {
    atomicAdd(&accum[3], a0);
    atomicAdd(&accum[4], a1);
    atomicAdd(&accum[5], a2);
  }
}

__global__ void k_final(const float* __restrict__ accum, float* __restrict__ out){
  if (threadIdx.x == 0) {
    out[0] = 0.001f * (-0.5f * accum[4] * (1.f/1024.f));       // kld
    out[1] = accum[0] * (1.f/524288.f);                        // root
    out[2] = accum[3] * (1.f/393216.f);                        // disp
    out[3] = 0.1f * (accum[5] * (1.f/131072.f));               // cons
    out[4] = 0.1f * (accum[2] * (1.f/9437184.f));              // fk
    out[5] = accum[1] * (1.f/12058624.f);                      // joints
  }
}

extern "C" void kernel_launch(void* const* d_in, const int* in_sizes, int n_in,
                              void* d_out, int out_size, void* d_ws, size_t ws_size,
                              hipStream_t stream)
{
  (void)in_sizes; (void)n_in; (void)out_size; (void)ws_size;
  const float* base = (const float*)d_in[0];
  const float* tmot = (const float*)d_in[1];
  const float* ind  = (const float*)d_in[2];
  const float* tgd  = (const float*)d_in[3];
  const float* mu   = (const float*)d_in[4];
  const float* lv   = (const float*)d_in[5];
  const float* lat  = (const float*)d_in[6];
  const float* W    = (const float*)d_in[7];
  const float* meanq= (const float*)d_in[8];
  const float* stdq = (const float*)d_in[9];
  const float* offs = (const float*)d_in[10];
  float* out = (float*)d_out;

  char* ws = (char*)d_ws;
  float* qs    = (float*)(ws);                      // 1024*12288*4 = 50331648
  float* G     = (float*)(ws + 50331648);           // 512*12288*4  = 25165824
  float* part  = (float*)(ws + 75497472);           // 16*512*256*4 = 8388608
  float* accum = (float*)(ws + 83886080);           // 8 floats

  hipLaunchKernelGGL(k_zero,     dim3(1),        dim3(64),  0, stream, accum);
  hipLaunchKernelGGL(k_decode,   dim3(96, 8),    dim3(256), 0, stream, base, lat, W, qs);
  hipLaunchKernelGGL(k_pose,     dim3(512),      dim3(128), 0, stream, qs, tmot, meanq, stdq, offs, G, accum);
  hipLaunchKernelGGL(k_gradgemm, dim3(2, 8, 16), dim3(256), 0, stream, G, W, part);
  hipLaunchKernelGGL(k_rest,     dim3(1536),     dim3(256), 0, stream, ind, tgd, mu, lv, lat, part, accum);
  hipLaunchKernelGGL(k_final,    dim3(1),        dim3(64),  0, stream, accum, out);
}

// Round 4
// 479.886 us; speedup vs baseline: 1.5580x; 1.5580x over previous
//
#include <hip/hip_runtime.h>
#include <utility>

#define DEVI __device__ __forceinline__

namespace {

constexpr int T_ = 128;
constexpr int NCH = 96;
constexpr int CT = NCH * T_;          // 12288
constexpr int NJ = 24;
constexpr int ZDIM = 256;
constexpr int PAR[NJ] = {0,0,0,0,1,2,3,4,5,6,7,8,9,9,9,12,13,14,16,17,18,19,20,21};

struct Q  { float w,x,y,z; };
struct V3 { float x,y,z; };

DEVI Q qmul(Q a, Q b){
  return Q{ a.w*b.w - a.x*b.x - a.y*b.y - a.z*b.z,
            a.w*b.x + a.x*b.w + a.y*b.z - a.z*b.y,
            a.w*b.y - a.x*b.z + a.y*b.w + a.z*b.x,
            a.w*b.z + a.x*b.y - a.y*b.x + a.z*b.w };
}
DEVI Q qconj(Q a){ return Q{a.w,-a.x,-a.y,-a.z}; }
DEVI float qn2(Q a){ return a.w*a.w + a.x*a.x + a.y*a.y + a.z*a.z; }
DEVI Q qscale(Q a, float s){ return Q{a.w*s, a.x*s, a.y*s, a.z*s}; }
DEVI Q qadd(Q a, Q b){ return Q{a.w+b.w, a.x+b.x, a.y+b.y, a.z+b.z}; }
DEVI Q qinv(Q a){ return qscale(qconj(a), 1.0f/qn2(a)); }
DEVI V3 qrot(Q g, V3 v){
  Q t = qmul(g, Q{0.f, v.x, v.y, v.z});
  Q y = qmul(t, qconj(g));
  float in = 1.0f/qn2(g);
  return V3{y.x*in, y.y*in, y.z*in};
}
DEVI Q qinv_bwd(Q q, Q g){
  float n  = qn2(q);
  float in = 1.0f/n;
  float d  = g.w*q.w - g.x*q.x - g.y*q.y - g.z*q.z;   // g . conj(q)
  float c  = 2.0f*d*in*in;
  return Q{ g.w*in - q.w*c, -g.x*in - q.x*c, -g.y*in - q.y*c, -g.z*in - q.z*c };
}
DEVI Q qrot_bwd_g(Q g, V3 v, V3 w){
  float in = 1.0f/qn2(g);
  Q u{0.f, v.x, v.y, v.z};
  Q t = qmul(g, u);
  Q y = qmul(t, qconj(g));
  Q G4{0.f, w.x*in, w.y*in, w.z*in};
  Q dt  = qmul(G4, g);
  Q dcg = qmul(qconj(t), G4);
  Q dg  = qconj(dcg);
  dg = qadd(dg, qmul(dt, qconj(u)));
  float wy = w.x*y.x + w.y*y.y + w.z*y.z;
  dg = qadd(dg, qscale(g, -2.0f*wy*in*in));
  return dg;
}

template<typename F, int... Is>
DEVI void sf_impl(F&& f, std::integer_sequence<int, Is...>){
  (f(std::integral_constant<int, Is>{}), ...);
}
template<int N, typename F>
DEVI void static_for(F&& f){ sf_impl(f, std::make_integer_sequence<int, N>{}); }

template<int Jj>
DEVI Q loadQ(const float (&q)[NJ][4]){ return Q{q[Jj][0], q[Jj][1], q[Jj][2], q[Jj][3]}; }
template<int Jj>
DEVI Q localQ(const float (&q)[NJ][4]){
  if constexpr (Jj < 4) return loadQ<Jj>(q);
  else return qmul(qinv(loadQ<PAR[Jj]>(q)), loadQ<Jj>(q));
}
template<int Jj>
DEVI Q grotRec(const float (&q)[NJ][4]){
  if constexpr (Jj == 0) return Q{1.f,0.f,0.f,0.f};
  else return qmul(grotRec<PAR[Jj]>(q), localQ<Jj>(q));
}

template<bool TGT, typename PJ>
DEVI void chainFwd(const float* __restrict__ base, int t,
                   const float* s_std, const float* s_mean, const float* s_off,
                   float (&q)[NJ][4], PJ&& pj)
{
  Q grot[NJ]; V3 gpos[NJ];
  static_for<NJ>([&](auto jc){
    constexpr int j = decltype(jc)::value;
    if constexpr (j == 0) {
      q[0][0]=1.f; q[0][1]=0.f; q[0][2]=0.f; q[0][3]=0.f;
      grot[0] = Q{1.f,0.f,0.f,0.f};
      gpos[0] = V3{0.f,0.f,0.f};
    } else {
      constexpr int P = PAR[j];
      #pragma unroll
      for (int i = 0; i < 4; ++i){
        const int c  = 4*j + i;
        const int oc = TGT ? (8*j + i) : c;
        q[j][i] = base[oc*T_ + t] * s_std[c] + s_mean[c];
      }
      Q qj{q[j][0], q[j][1], q[j][2], q[j][3]};
      Q L;
      if constexpr (j < 4) L = qj;
      else L = qmul(qinv(Q{q[P][0], q[P][1], q[P][2], q[P][3]}), qj);
      Q gP = grot[P];
      grot[j] = qmul(gP, L);
      V3 o{s_off[3*j], s_off[3*j+1], s_off[3*j+2]};
      V3 r = qrot(gP, o);
      gpos[j] = V3{gpos[P].x + r.x, gpos[P].y + r.y, gpos[P].z + r.z};
    }
    pj(jc, gpos[j]);
  });
}

DEVI void chainBwd(const float (&q)[NJ][4], const float* s_std, const float* s_off,
                   V3 (&dgp)[NJ], float* __restrict__ Gp, int t)
{
  Q dgr[NJ] = {};
  Q dq [NJ] = {};
  static_for<NJ-1>([&](auto ic){
    constexpr int j = NJ - 1 - decltype(ic)::value;   // 23..1
    constexpr int P = PAR[j];
    V3 w = dgp[j];
    Q gP = grotRec<P>(q);
    if constexpr (P != 0) {
      dgp[P].x += w.x; dgp[P].y += w.y; dgp[P].z += w.z;
      V3 o{s_off[3*j], s_off[3*j+1], s_off[3*j+2]};
      dgr[P] = qadd(dgr[P], qrot_bwd_g(gP, o, w));
    }
    Q Gj = dgr[j];
    Q dL = qmul(qconj(gP), Gj);
    if constexpr (P != 0) {
      dgr[P] = qadd(dgr[P], qmul(Gj, qconj(localQ<j>(q))));
    }
    if constexpr (j < 4) {
      dq[j] = qadd(dq[j], dL);
    } else {
      Q qP  = loadQ<P>(q);
      Q iqP = qinv(qP);
      dq[j] = qadd(dq[j], qmul(qconj(iqP), dL));
      Q dInv = qmul(dL, qconj(loadQ<j>(q)));
      dq[P] = qadd(dq[P], qinv_bwd(qP, dInv));
    }
    Gp[(4*j+0)*T_ + t] = dq[j].w * s_std[4*j+0];
    Gp[(4*j+1)*T_ + t] = dq[j].x * s_std[4*j+1];
    Gp[(4*j+2)*T_ + t] = dq[j].y * s_std[4*j+2];
    Gp[(4*j+3)*T_ + t] = dq[j].z * s_std[4*j+3];
  });
  #pragma unroll
  for (int i = 0; i < 4; ++i) Gp[i*T_ + t] = 0.f;
}

DEVI float waveSum(float v){
  #pragma unroll
  for (int o = 32; o > 0; o >>= 1) v += __shfl_down(v, o);
  return v;
}

} // namespace

// ---------------- kernels ----------------

// qs = base_motion + lat @ W_dec : M=1024, N=12288, K=256
__global__ __launch_bounds__(256) void k_decode(
    const float* __restrict__ base, const float* __restrict__ lat,
    const float* __restrict__ W, float* __restrict__ qs)
{
  __shared__ float As[32][132];
  __shared__ float Bs[32][128];
  const int tid = threadIdx.x;
  const int bn = blockIdx.x * 128;
  const int bm = blockIdx.y * 128;
  float acc[8][8] = {};
  for (int k0 = 0; k0 < 256; k0 += 32) {
    #pragma unroll
    for (int r = 0; r < 4; ++r) {
      int idx = r*256 + tid;
      int row = idx >> 3;
      int kc  = (idx & 7) << 2;
      float4 v = *(const float4*)&lat[(size_t)(bm + row)*256 + k0 + kc];
      As[kc+0][row] = v.x; As[kc+1][row] = v.y;
      As[kc+2][row] = v.z; As[kc+3][row] = v.w;
    }
    #pragma unroll
    for (int r = 0; r < 4; ++r) {
      int idx = r*256 + tid;
      int kr = idx >> 5;
      int nc = (idx & 31) << 2;
      *(float4*)&Bs[kr][nc] = *(const float4*)&W[(size_t)(k0 + kr)*CT + bn + nc];
    }
    __syncthreads();
    const int tx = tid & 15, ty = tid >> 4;
    #pragma unroll
    for (int kk = 0; kk < 32; ++kk) {
      float a[8], b[8];
      float4 a0 = *(float4*)&As[kk][ty*8];
      float4 a1 = *(float4*)&As[kk][ty*8+4];
      float4 b0 = *(float4*)&Bs[kk][tx*8];
      float4 b1 = *(float4*)&Bs[kk][tx*8+4];
      a[0]=a0.x;a[1]=a0.y;a[2]=a0.z;a[3]=a0.w;a[4]=a1.x;a[5]=a1.y;a[6]=a1.z;a[7]=a1.w;
      b[0]=b0.x;b[1]=b0.y;b[2]=b0.z;b[3]=b0.w;b[4]=b1.x;b[5]=b1.y;b[6]=b1.z;b[7]=b1.w;
      #pragma unroll
      for (int i = 0; i < 8; ++i)
        #pragma unroll
        for (int j = 0; j < 8; ++j) acc[i][j] += a[i]*b[j];
    }
    __syncthreads();
  }
  const int tx = tid & 15, ty = tid >> 4;
  #pragma unroll
  for (int i = 0; i < 8; ++i) {
    size_t row = bm + ty*8 + i;
    #pragma unroll
    for (int j = 0; j < 8; j += 4) {
      size_t col = bn + tx*8 + j;
      float4 bv = *(const float4*)&base[row*CT + col];
      float4 o;
      o.x = bv.x + acc[i][j+0]; o.y = bv.y + acc[i][j+1];
      o.z = bv.z + acc[i][j+2]; o.w = bv.w + acc[i][j+3];
      *(float4*)&qs[row*CT + col] = o;
    }
  }
}

// Per (p,t): elementwise root/joint losses, 4 FK chains, fk loss, backward -> G
__global__ __launch_bounds__(128, 1) void k_pose(
    const float* __restrict__ qs,   const float* __restrict__ tmot,
    const float* __restrict__ meanq,const float* __restrict__ stdq,
    const float* __restrict__ offs, float* __restrict__ G,
    float* __restrict__ bpose)
{
  __shared__ float s_std[96], s_mean[96], s_off[72];
  __shared__ float sred[3][2];
  const int p = blockIdx.x;
  const int t = threadIdx.x;
  if (t < 96) { s_std[t] = stdq[t]; s_mean[t] = meanq[t]; }
  if (t < 72) s_off[t] = offs[p*72 + t];
  __syncthreads();

  const float* qs0 = qs   + (size_t)(2*p) * CT;
  const float* qs1 = qs0  + CT;
  const float* tm0 = tmot + (size_t)(2*p) * (2*CT);
  const float* tm1 = tm0  + 2*CT;

  float accR = 0.f, accJ = 0.f;
  #pragma unroll 4
  for (int c = 0; c < 4; ++c) {
    int oc = ((c >> 2) << 3) + (c & 3);
    float d0 = qs0[c*T_ + t] - tm0[oc*T_ + t];
    float d1 = qs1[c*T_ + t] - tm1[oc*T_ + t];
    accR += d0*d0 + d1*d1;
  }
  #pragma unroll 4
  for (int c = 4; c < 96; ++c) {
    int oc = ((c >> 2) << 3) + (c & 3);
    float d0 = qs0[c*T_ + t] - tm0[oc*T_ + t];
    float d1 = qs1[c*T_ + t] - tm1[oc*T_ + t];
    accJ += d0*d0 + d1*d1;
  }

  float fkAcc = 0.f;
  V3 posA[NJ], posB[NJ];
  float qtmp[NJ][4], qd0[NJ][4];

  chainFwd<true >(tm0, t, s_std, s_mean, s_off, qtmp,
    [&](auto jc, V3 g){ posA[decltype(jc)::value] = g; });
  chainFwd<false>(qs0, t, s_std, s_mean, s_off, qd0,
    [&](auto jc, V3 g){
      constexpr int j = decltype(jc)::value;
      float dx = g.x - posA[j].x, dy = g.y - posA[j].y, dz = g.z - posA[j].z;
      fkAcc += dx*dx + dy*dy + dz*dz;
      posB[j] = g;
    });
  chainFwd<true >(tm1, t, s_std, s_mean, s_off, qtmp,
    [&](auto jc, V3 g){ posA[decltype(jc)::value] = g; });
  V3 dgp[NJ];
  chainFwd<false>(qs1, t, s_std, s_mean, s_off, qtmp,
    [&](auto jc, V3 g){
      constexpr int j = decltype(jc)::value;
      float dx = g.x - posA[j].x, dy = g.y - posA[j].y, dz = g.z - posA[j].z;
      fkAcc += dx*dx + dy*dy + dz*dz;
      dgp[j] = V3{2.f*(posB[j].x - g.x), 2.f*(posB[j].y - g.y), 2.f*(posB[j].z - g.z)};
    });

  chainBwd(qd0, s_std, s_off, dgp, G + (size_t)p * CT, t);

  float r  = waveSum(accR);
  float jj = waveSum(accJ);
  float fk = waveSum(fkAcc);
  const int wid = t >> 6;
  if ((t & 63) == 0) { sred[0][wid] = r; sred[1][wid] = jj; sred[2][wid] = fk; }
  __syncthreads();
  if (t == 0) {
    bpose[p]        = sred[0][0] + sred[0][1];
    bpose[512 + p]  = sred[1][0] + sred[1][1];
    bpose[1024 + p] = sred[2][0] + sred[2][1];
  }
}

// grad partials: part[s][p][z], SPLITK=16, K-chunk 768 (256 blocks -> full CU coverage)
__global__ __launch_bounds__(256) void k_gradgemm(
    const float* __restrict__ G, const float* __restrict__ W,
    float* __restrict__ part)
{
  __shared__ float As[64][33];
  __shared__ float Bs[128][33];
  const int tid = threadIdx.x;
  const int bn = blockIdx.x * 128;
  const int bm = blockIdx.y * 64;
  const int s  = blockIdx.z;
  const int kb = s * 768;
  float acc[4][8] = {};
  for (int k0 = 0; k0 < 768; k0 += 32) {
    #pragma unroll
    for (int r = 0; r < 2; ++r) {
      int idx = r*256 + tid;
      int row = idx >> 3;
      int kc  = (idx & 7) << 2;
      float4 v = *(const float4*)&G[(size_t)(bm + row)*CT + kb + k0 + kc];
      As[row][kc+0]=v.x; As[row][kc+1]=v.y; As[row][kc+2]=v.z; As[row][kc+3]=v.w;
    }
    #pragma unroll
    for (int r = 0; r < 4; ++r) {
      int idx = r*256 + tid;
      int row = idx >> 3;
      int kc  = (idx & 7) << 2;
      float4 v = *(const float4*)&W[(size_t)(bn + row)*CT + kb + k0 + kc];
      Bs[row][kc+0]=v.x; Bs[row][kc+1]=v.y; Bs[row][kc+2]=v.z; Bs[row][kc+3]=v.w;
    }
    __syncthreads();
    const int tx = tid & 15, ty = tid >> 4;
    #pragma unroll
    for (int kk = 0; kk < 32; ++kk) {
      float a[4], b[8];
      #pragma unroll
      for (int i = 0; i < 4; ++i) a[i] = As[ty*4+i][kk];
      #pragma unroll
      for (int j = 0; j < 8; ++j) b[j] = Bs[tx*8+j][kk];
      #pragma unroll
      for (int i = 0; i < 4; ++i)
        #pragma unroll
        for (int j = 0; j < 8; ++j) acc[i][j] += a[i]*b[j];
    }
    __syncthreads();
  }
  const int tx = tid & 15, ty = tid >> 4;
  #pragma unroll
  for (int i = 0; i < 4; ++i) {
    size_t pr = (size_t)s*131072 + (size_t)(bm + ty*4 + i)*256 + bn + tx*8;
    float4 o0{acc[i][0], acc[i][1], acc[i][2], acc[i][3]};
    float4 o1{acc[i][4], acc[i][5], acc[i][6], acc[i][7]};
    *(float4*)&part[pr]   = o0;
    *(float4*)&part[pr+4] = o1;
  }
}

// disp / kld / cons reductions — float4, block-partial, no atomics
__global__ __launch_bounds__(256) void k_rest(
    const float* __restrict__ ind, const float* __restrict__ tgd,
    const float* __restrict__ mu,  const float* __restrict__ lv,
    const float* __restrict__ lat, const float* __restrict__ part,
    float* __restrict__ brest)
{
  __shared__ float sred[3][4];
  const int t = threadIdx.x;
  const int gid = blockIdx.x * 256 + t;            // 0..131071
  float a0 = 0.f, a1 = 0.f, a2 = 0.f;
  if (gid < 98304) {
    float4 a = ((const float4*)ind)[gid];
    float4 b = ((const float4*)tgd)[gid];
    float dx=a.x-b.x, dy=a.y-b.y, dz=a.z-b.z, dw=a.w-b.w;
    a0 = dx*dx + dy*dy + dz*dz + dw*dw;
  }
  if (gid < 65536) {
    float4 l = ((const float4*)lv)[gid];
    float4 m = ((const float4*)mu)[gid];
    a1 = (1.f + l.x - m.x*m.x - __expf(l.x)) + (1.f + l.y - m.y*m.y - __expf(l.y))
       + (1.f + l.z - m.z*m.z - __expf(l.z)) + (1.f + l.w - m.w*m.w - __expf(l.w));
  }
  if (gid < 32768) {
    float4 g{0.f,0.f,0.f,0.f};
    #pragma unroll
    for (int s = 0; s < 16; ++s) {
      float4 v = ((const float4*)(part + (size_t)s*131072))[gid];
      g.x += v.x; g.y += v.y; g.z += v.z; g.w += v.w;
    }
    int p  = gid >> 6;
    int zb = (gid & 63) << 2;
    float4 La = *(const float4*)&lat[(size_t)(2*p)*ZDIM + zb];
    float4 Lb = *(const float4*)&lat[(size_t)(2*p+1)*ZDIM + zb];
    float vx = La.x - g.x - Lb.x, vy = La.y - g.y - Lb.y;
    float vz = La.z - g.z - Lb.z, vw = La.w - g.w - Lb.w;
    a2 = vx*vx + vy*vy + vz*vz + vw*vw;
  }
  a0 = waveSum(a0); a1 = waveSum(a1); a2 = waveSum(a2);
  const int wid = t >> 6;
  if ((t & 63) == 0) { sred[0][wid]=a0; sred[1][wid]=a1; sred[2][wid]=a2; }
  __syncthreads();
  if (t == 0) {
    brest[blockIdx.x]        = sred[0][0]+sred[0][1]+sred[0][2]+sred[0][3];
    brest[512 + blockIdx.x]  = sred[1][0]+sred[1][1]+sred[1][2]+sred[1][3];
    brest[1024 + blockIdx.x] = sred[2][0]+sred[2][1]+sred[2][2]+sred[2][3];
  }
}

__global__ __launch_bounds__(256) void k_final(
    const float* __restrict__ bpose, const float* __restrict__ brest,
    float* __restrict__ out)
{
  __shared__ float sred[4];
  const int t = threadIdx.x;
  float tot[6];
  const float* srcs[6] = { bpose, bpose+512, bpose+1024, brest, brest+512, brest+1024 };
  #pragma unroll
  for (int c = 0; c < 6; ++c) {
    float x = srcs[c][t] + srcs[c][t+256];
    x = waveSum(x);
    if ((t & 63) == 0) sred[t>>6] = x;
    __syncthreads();
    tot[c] = sred[0]+sred[1]+sred[2]+sred[3];
    __syncthreads();
  }
  if (t == 0) {
    out[0] = 0.001f * (-0.5f * tot[4] * (1.f/1024.f));       // kld
    out[1] = tot[0] * (1.f/524288.f);                        // root
    out[2] = tot[3] * (1.f/393216.f);                        // disp
    out[3] = 0.1f * (tot[5] * (1.f/131072.f));               // cons
    out[4] = 0.1f * (tot[2] * (1.f/9437184.f));              // fk
    out[5] = tot[1] * (1.f/12058624.f);                      // joints
  }
}

extern "C" void kernel_launch(void* const* d_in, const int* in_sizes, int n_in,
                              void* d_out, int out_size, void* d_ws, size_t ws_size,
                              hipStream_t stream)
{
  (void)in_sizes; (void)n_in; (void)out_size; (void)ws_size;
  const float* base = (const float*)d_in[0];
  const float* tmot = (const float*)d_in[1];
  const float* ind  = (const float*)d_in[2];
  const float* tgd  = (const float*)d_in[3];
  const float* mu   = (const float*)d_in[4];
  const float* lv   = (const float*)d_in[5];
  const float* lat  = (const float*)d_in[6];
  const float* W    = (const float*)d_in[7];
  const float* meanq= (const float*)d_in[8];
  const float* stdq = (const float*)d_in[9];
  const float* offs = (const float*)d_in[10];
  float* out = (float*)d_out;

  char* ws = (char*)d_ws;
  float* qs    = (float*)(ws);                      // 50331648 B
  float* G     = (float*)(ws + 50331648);           // 25165824 B
  float* part  = (float*)(ws + 75497472);           // 16*512*256*4 = 8388608 B
  float* bpose = (float*)(ws + 83886080);           // 3*512*4 = 6144 B
  float* brest = (float*)(ws + 83892224);           // 6144 B

  hipLaunchKernelGGL(k_decode,   dim3(96, 8),    dim3(256), 0, stream, base, lat, W, qs);
  hipLaunchKernelGGL(k_pose,     dim3(512),      dim3(128), 0, stream, qs, tmot, meanq, stdq, offs, G, bpose);
  hipLaunchKernelGGL(k_gradgemm, dim3(2, 8, 16), dim3(256), 0, stream, G, W, part);
  hipLaunchKernelGGL(k_rest,     dim3(512),      dim3(256), 0, stream, ind, tgd, mu, lv, lat, part, brest);
  hipLaunchKernelGGL(k_final,    dim3(1),        dim3(256), 0, stream, bpose, brest, out);
}